// Round 1
// 238.099 us; speedup vs baseline: 1.1466x; 1.1466x over previous
//
#include <hip/hip_runtime.h>

typedef _Float16 half8 __attribute__((ext_vector_type(8)));
typedef _Float16 half4 __attribute__((ext_vector_type(4)));
typedef _Float16 half2v __attribute__((ext_vector_type(2)));
typedef float floatx4 __attribute__((ext_vector_type(4)));
typedef float floatx2 __attribute__((ext_vector_type(2)));

#define MFMA_F16 __builtin_amdgcn_mfma_f32_16x16x32_f16
#define FREQ (-0.41524101186092f)   // -log2(10000)/32

// B=2,H=16,L=8192,D=64,WINDOW=512. Grid 1024 x 512 threads.
// Block = half-window (256 q rows), 8 waves x 32 q-rows each.
// Window's two blocks are 8 apart -> same XCD.
__global__ __launch_bounds__(512, 4) void swa4(
    const float* __restrict__ Q, const float* __restrict__ K,
    const float* __restrict__ V, const int* __restrict__ pid,
    float* __restrict__ Out)
{
    __shared__ __align__(16) _Float16 lq[128 * 72];       // Q rope staging (2 rounds)
    __shared__ __align__(16) _Float16 lk[2][32 * 64];     // roped K chunk, XOR-swizzled, dbuf
    __shared__ __align__(16) _Float16 lvt[2][64 * 32];    // V^T chunk, XOR-swizzled, dbuf
    __shared__ __align__(16) _Float16 lp[8][16 * 40];     // per-wave P transpose buffer

    const int bid   = blockIdx.x;
    const int half_ = (bid >> 3) & 1;                     // which half-window
    const int win   = (bid & 7) | ((bid >> 4) << 3);      // 0..511
    const int n = win & 15, bh = win >> 4;
    const long long winrow = (long long)bh * 8192 + n * 512;
    const long long qbase  = winrow + half_ * 256;
    const float* Qb = Q + qbase * 64;
    const float* Kb = K + winrow * 64;
    const float* Vb = V + winrow * 64;
    float* Ob = Out + qbase * 64;
    const int pidq = n * 512 + half_ * 256;
    const int pidk = n * 512;

    const int tid = threadIdx.x, lane = tid & 63, wv = tid >> 6;  // wv 0..7
    const int l15 = lane & 15, quad = (lane >> 4) & 3;
    const float CS = 0.125f * 1.44269504088896f;          // 1/sqrt(D)*log2(e)

    // ---------- Q fragments: 2 rounds of 128 rows through lq ----------
    half8 qf[2][2];
    {
        const int rowl = tid >> 2;          // 0..127 within round
        const int dq   = (tid & 3) * 8;     // pair-dim start
        float ifq[8];
        #pragma unroll
        for (int i = 0; i < 8; ++i) ifq[i] = __builtin_exp2f((float)(dq + i) * FREQ);
        for (int rnd = 0; rnd < 2; ++rnd) {
            const float* src = Qb + (rnd * 128 + rowl) * 64;
            float pos = (float)pid[pidq + rnd * 128 + rowl];
            float4 a0 = *(const float4*)(src + dq);
            float4 a1 = *(const float4*)(src + dq + 4);
            float4 b0 = *(const float4*)(src + 32 + dq);
            float4 b1 = *(const float4*)(src + 36 + dq);
            float lo[8] = {a0.x,a0.y,a0.z,a0.w,a1.x,a1.y,a1.z,a1.w};
            float hi[8] = {b0.x,b0.y,b0.z,b0.w,b1.x,b1.y,b1.z,b1.w};
            half8 wlo, whi;
            #pragma unroll
            for (int i = 0; i < 8; ++i) {
                float sn, cn;
                __sincosf(pos * ifq[i], &sn, &cn);
                wlo[i] = (_Float16)((lo[i] * cn - hi[i] * sn) * CS);
                whi[i] = (_Float16)((hi[i] * cn + lo[i] * sn) * CS);
            }
            if (rnd) __syncthreads();       // round-0 frag reads done
            *(half8*)&lq[rowl * 72 + dq]      = wlo;
            *(half8*)&lq[rowl * 72 + 32 + dq] = whi;
            __syncthreads();
            if ((wv >> 2) == rnd) {
                const int rb = (wv & 3) * 32;
                #pragma unroll
                for (int rt = 0; rt < 2; ++rt) {
                    qf[rt][0] = *(const half8*)&lq[(rb + rt * 16 + l15) * 72 + quad * 8];
                    qf[rt][1] = *(const half8*)&lq[(rb + rt * 16 + l15) * 72 + 32 + quad * 8];
                }
            }
        }
    }

    floatx4 o[2][4], ol[2];
    #pragma unroll
    for (int rt = 0; rt < 2; ++rt) {
        ol[rt] = (floatx4){0.f, 0.f, 0.f, 0.f};
        #pragma unroll
        for (int vt = 0; vt < 4; ++vt) o[rt][vt] = (floatx4){0.f, 0.f, 0.f, 0.f};
    }
    half8 onesf;
    #pragma unroll
    for (int i = 0; i < 8; ++i) onesf[i] = (_Float16)1.0f;

    // staging roles (512 threads)
    const int key = tid >> 4;            // 0..31 (K rope: one key, 2 dim-pairs)
    const int pr  = tid & 15;            // pair group: dims 2*pr, 2*pr+1
    const int dv  = tid & 63;            // V gather column
    const int grp = tid >> 6;            // 0..7 -> V keys grp*4..grp*4+3
    float if2[2];
    #pragma unroll
    for (int i = 0; i < 2; ++i) if2[i] = __builtin_exp2f((float)(pr * 2 + i) * FREQ);
    const int klo_addr = key * 64 + (((pr >> 2) ^ (key & 7)) * 8) + (pr & 3) * 2;
    const int khi_addr = key * 64 + ((((pr >> 2) + 4) ^ (key & 7)) * 8) + (pr & 3) * 2;
    const int vst_addr = dv * 32 + (((grp >> 1) ^ ((dv >> 1) & 3)) * 8) + (grp & 1) * 4;
    const int ksw0 = (quad ^ (l15 & 7)) * 8;
    const int ksw1 = ((quad + 4) ^ (l15 & 7)) * 8;
    const int vsw  = (quad ^ ((l15 >> 1) & 3)) * 8;

    // prologue: prefetch chunk 0
    floatx2 ka  = *(const floatx2*)(Kb + key * 64 + pr * 2);
    floatx2 kb2 = *(const floatx2*)(Kb + key * 64 + 32 + pr * 2);
    float vr[4];
    #pragma unroll
    for (int i = 0; i < 4; ++i) vr[i] = Vb[(grp * 4 + i) * 64 + dv];
    int kp = pid[pidk + key];

    for (int kc = 0; kc < 16; ++kc) {
        const int cur = kc & 1;
        // rope K regs -> f16
        float kpos = (float)kp;
        half2v klo, khi;
        {
            float a[2] = {ka.x, ka.y};
            float b[2] = {kb2.x, kb2.y};
            #pragma unroll
            for (int i = 0; i < 2; ++i) {
                float sn, cn;
                __sincosf(kpos * if2[i], &sn, &cn);
                klo[i] = (_Float16)(a[i] * cn - b[i] * sn);
                khi[i] = (_Float16)(b[i] * cn + a[i] * sn);
            }
        }
        half4 vh;
        #pragma unroll
        for (int i = 0; i < 4; ++i) vh[i] = (_Float16)vr[i];

        *(half2v*)&lk[cur][klo_addr] = klo;
        *(half2v*)&lk[cur][khi_addr] = khi;
        *(half4*)&lvt[cur][vst_addr] = vh;
        __syncthreads();                  // writes of buf[cur] visible; prev buf reads done

        // prefetch next chunk while computing this one
        if (kc < 15) {
            const float* kn = Kb + (kc + 1) * 2048;
            const float* vn = Vb + (kc + 1) * 2048;
            ka  = *(const floatx2*)(kn + key * 64 + pr * 2);
            kb2 = *(const floatx2*)(kn + key * 64 + 32 + pr * 2);
            #pragma unroll
            for (int i = 0; i < 4; ++i) vr[i] = vn[(grp * 4 + i) * 64 + dv];
            kp = pid[pidk + (kc + 1) * 32 + key];
        }

        // fragments (shared across row-tiles)
        half8 kf00 = *(const half8*)&lk[cur][l15 * 64 + ksw0];
        half8 kf01 = *(const half8*)&lk[cur][l15 * 64 + ksw1];
        half8 kf10 = *(const half8*)&lk[cur][(16 + l15) * 64 + ksw0];
        half8 kf11 = *(const half8*)&lk[cur][(16 + l15) * 64 + ksw1];
        half8 vf[4];
        #pragma unroll
        for (int vt = 0; vt < 4; ++vt)
            vf[vt] = *(const half8*)&lvt[cur][(vt * 16 + l15) * 32 + vsw];

        #pragma unroll
        for (int rt = 0; rt < 2; ++rt) {
            floatx4 s0 = {0.f,0.f,0.f,0.f}, s1 = {0.f,0.f,0.f,0.f};
            s0 = MFMA_F16(qf[rt][0], kf00, s0, 0, 0, 0);
            s0 = MFMA_F16(qf[rt][1], kf01, s0, 0, 0, 0);
            s1 = MFMA_F16(qf[rt][0], kf10, s1, 0, 0, 0);
            s1 = MFMA_F16(qf[rt][1], kf11, s1, 0, 0, 0);

            #pragma unroll
            for (int r = 0; r < 4; ++r) {
                float p0 = __builtin_exp2f(s0[r]);
                float p1 = __builtin_exp2f(s1[r]);
                lp[wv][(quad * 4 + r) * 40 + l15]      = (_Float16)p0;
                lp[wv][(quad * 4 + r) * 40 + 16 + l15] = (_Float16)p1;
            }
            half8 pf = *(const half8*)&lp[wv][l15 * 40 + quad * 8];
            ol[rt] = MFMA_F16(pf, onesf, ol[rt], 0, 0, 0);
            #pragma unroll
            for (int vt = 0; vt < 4; ++vt)
                o[rt][vt] = MFMA_F16(pf, vf[vt], o[rt][vt], 0, 0, 0);
        }
    }

    // ---------- epilogue ----------
    #pragma unroll
    for (int rt = 0; rt < 2; ++rt) {
        #pragma unroll
        for (int r = 0; r < 4; ++r) {
            int rowl = wv * 32 + rt * 16 + quad * 4 + r;   // 0..255
            int j = half_ * 256 + rowl;                    // row within window
            float w;
            if (n == 0 || n == 15)  w = 1.0f;
            else if (j < 64)        w = (float)j * (1.0f / 63.0f);
            else if (j >= 448)      w = (float)(511 - j) * (1.0f / 63.0f);
            else                    w = 1.0f;
            float f = (w / (w + 1e-8f)) / ol[rt][r];
            #pragma unroll
            for (int vt = 0; vt < 4; ++vt)
                Ob[rowl * 64 + vt * 16 + l15] = o[rt][vt][r] * f;
        }
    }
}

extern "C" void kernel_launch(void* const* d_in, const int* in_sizes, int n_in,
                              void* d_out, int out_size, void* d_ws, size_t ws_size,
                              hipStream_t stream) {
    const float* q   = (const float*)d_in[0];
    const float* k   = (const float*)d_in[1];
    const float* v   = (const float*)d_in[2];
    const int*   pid = (const int*)d_in[3];
    float* out = (float*)d_out;
    (void)in_sizes; (void)n_in; (void)out_size; (void)d_ws; (void)ws_size;
    swa4<<<dim3(1024), dim3(512), 0, stream>>>(q, k, v, pid, out);
}

// Round 4
// 234.503 us; speedup vs baseline: 1.1641x; 1.0153x over previous
//
#include <hip/hip_runtime.h>

typedef _Float16 half8 __attribute__((ext_vector_type(8)));
typedef _Float16 half4 __attribute__((ext_vector_type(4)));
typedef _Float16 half2v __attribute__((ext_vector_type(2)));
typedef float floatx4 __attribute__((ext_vector_type(4)));
typedef float floatx2 __attribute__((ext_vector_type(2)));

#define MFMA_F16 __builtin_amdgcn_mfma_f32_16x16x32_f16
#define FREQ (-0.41524101186092f)   // -log2(10000)/32

static __device__ __forceinline__ unsigned pack_f16(float a, float b) {
    half2v h; h.x = (_Float16)a; h.y = (_Float16)b;   // RTE converts + pack
    return __builtin_bit_cast(unsigned, h);
}

// B=2,H=16,L=8192,D=64,WINDOW=512. Grid 1024 x 512 threads.
// Block = half-window (256 q rows), 8 waves x 32 q-rows each.
// Swapped QK^T: split-K operand layout makes P^T C-result the exact PV
// A-fragment -> softmax fully in-register, no LDS P buffer, no cross-lane.
__global__ __launch_bounds__(512, 4) void swa6(
    const float* __restrict__ Q, const float* __restrict__ K,
    const float* __restrict__ V, const int* __restrict__ pid,
    float* __restrict__ Out)
{
    __shared__ __align__(16) _Float16 lq[128 * 72];       // Q rope staging (2 rounds)
    __shared__ __align__(16) _Float16 lk[2][32 * 64];     // roped K chunk, XOR-swizzled, dbuf
    __shared__ __align__(16) _Float16 lvt[2][64 * 32];    // V^T chunk, XOR-swizzled, dbuf

    const int bid   = blockIdx.x;
    const int half_ = (bid >> 3) & 1;                     // which half-window
    const int win   = (bid & 7) | ((bid >> 4) << 3);      // 0..511
    const int n = win & 15, bh = win >> 4;
    const long long winrow = (long long)bh * 8192 + n * 512;
    const long long qbase  = winrow + half_ * 256;
    const float* Qb = Q + qbase * 64;
    const float* Kb = K + winrow * 64;
    const float* Vb = V + winrow * 64;
    float* Ob = Out + qbase * 64;
    const int pidq = n * 512 + half_ * 256;
    const int pidk = n * 512;

    const int tid = threadIdx.x, lane = tid & 63, wv = tid >> 6;  // wv 0..7
    const int l15 = lane & 15, quad = (lane >> 4) & 3;
    const float CS = 0.125f * 1.44269504088896f;          // 1/sqrt(D)*log2(e)

    // ---------- Q fragments: 2 rounds of 128 rows through lq ----------
    half8 qf[2][2];
    {
        const int rowl = tid >> 2;          // 0..127 within round
        const int dq   = (tid & 3) * 8;     // pair-dim start
        float ifq[8];
        #pragma unroll
        for (int i = 0; i < 8; ++i) ifq[i] = __builtin_exp2f((float)(dq + i) * FREQ);
        for (int rnd = 0; rnd < 2; ++rnd) {
            const float* src = Qb + (rnd * 128 + rowl) * 64;
            float pos = (float)pid[pidq + rnd * 128 + rowl];
            float4 a0 = *(const float4*)(src + dq);
            float4 a1 = *(const float4*)(src + dq + 4);
            float4 b0 = *(const float4*)(src + 32 + dq);
            float4 b1 = *(const float4*)(src + 36 + dq);
            float lo[8] = {a0.x,a0.y,a0.z,a0.w,a1.x,a1.y,a1.z,a1.w};
            float hi[8] = {b0.x,b0.y,b0.z,b0.w,b1.x,b1.y,b1.z,b1.w};
            half8 wlo, whi;
            #pragma unroll
            for (int i = 0; i < 8; ++i) {
                float sn, cn;
                __sincosf(pos * ifq[i], &sn, &cn);
                wlo[i] = (_Float16)((lo[i] * cn - hi[i] * sn) * CS);
                whi[i] = (_Float16)((hi[i] * cn + lo[i] * sn) * CS);
            }
            if (rnd) __syncthreads();       // round-0 frag reads done
            *(half8*)&lq[rowl * 72 + dq]      = wlo;
            *(half8*)&lq[rowl * 72 + 32 + dq] = whi;
            __syncthreads();
            if ((wv >> 2) == rnd) {
                const int rb = (wv & 3) * 32;
                #pragma unroll
                for (int rt = 0; rt < 2; ++rt) {
                    qf[rt][0] = *(const half8*)&lq[(rb + rt * 16 + l15) * 72 + quad * 8];
                    qf[rt][1] = *(const half8*)&lq[(rb + rt * 16 + l15) * 72 + 32 + quad * 8];
                }
            }
        }
    }

    floatx4 o[2][4], ol[2];
    #pragma unroll
    for (int rt = 0; rt < 2; ++rt) {
        ol[rt] = (floatx4){0.f, 0.f, 0.f, 0.f};
        #pragma unroll
        for (int vt = 0; vt < 4; ++vt) o[rt][vt] = (floatx4){0.f, 0.f, 0.f, 0.f};
    }
    half8 onesf;
    #pragma unroll
    for (int i = 0; i < 8; ++i) onesf[i] = (_Float16)1.0f;

    // staging roles (512 threads)
    const int key = tid >> 4;            // 0..31 (K rope: one key, 2 dim-pairs)
    const int pr  = tid & 15;            // pair group: dims 2*pr, 2*pr+1
    const int dv  = tid & 63;            // V gather column
    const int grp = tid >> 6;            // 0..7 -> V keys grp*4..grp*4+3
    float if2[2];
    #pragma unroll
    for (int i = 0; i < 2; ++i) if2[i] = __builtin_exp2f((float)(pr * 2 + i) * FREQ);
    const int klo_addr = key * 64 + (((pr >> 2) ^ (key & 7)) * 8) + (pr & 3) * 2;
    const int khi_addr = key * 64 + ((((pr >> 2) + 4) ^ (key & 7)) * 8) + (pr & 3) * 2;
    // V store: key-group g=grp (keys 4g..4g+3) at octet slot (g&3)^swz, sub (g>>2)*4.
    // A b128 read at octet quad then yields [keys 4q..4q+3 | keys 16+4q..19+4q].
    const int vst_addr = dv * 32 + (((grp & 3) ^ ((dv >> 1) & 3)) * 8) + (grp >> 2) * 4;
    const int ksw0 = (quad ^ (l15 & 7)) * 8;
    const int ksw1 = ((quad + 4) ^ (l15 & 7)) * 8;
    const int vsw  = (quad ^ ((l15 >> 1) & 3)) * 8;

    // prologue: prefetch chunk 0
    floatx2 ka  = *(const floatx2*)(Kb + key * 64 + pr * 2);
    floatx2 kb2 = *(const floatx2*)(Kb + key * 64 + 32 + pr * 2);
    float vr[4];
    #pragma unroll
    for (int i = 0; i < 4; ++i) vr[i] = Vb[(grp * 4 + i) * 64 + dv];
    int kp = pid[pidk + key];

    for (int kc = 0; kc < 16; ++kc) {
        const int cur = kc & 1;
        // rope K regs -> f16
        float kpos = (float)kp;
        half2v klo, khi;
        {
            float a[2] = {ka.x, ka.y};
            float b[2] = {kb2.x, kb2.y};
            #pragma unroll
            for (int i = 0; i < 2; ++i) {
                float sn, cn;
                __sincosf(kpos * if2[i], &sn, &cn);
                klo[i] = (_Float16)(a[i] * cn - b[i] * sn);
                khi[i] = (_Float16)(b[i] * cn + a[i] * sn);
            }
        }
        half4 vh;
        #pragma unroll
        for (int i = 0; i < 4; ++i) vh[i] = (_Float16)vr[i];

        *(half2v*)&lk[cur][klo_addr] = klo;
        *(half2v*)&lk[cur][khi_addr] = khi;
        *(half4*)&lvt[cur][vst_addr] = vh;
        __syncthreads();                  // writes of buf[cur] visible; prev buf reads done

        // prefetch next chunk while computing this one
        if (kc < 15) {
            const float* kn = Kb + (kc + 1) * 2048;
            const float* vn = Vb + (kc + 1) * 2048;
            ka  = *(const floatx2*)(kn + key * 64 + pr * 2);
            kb2 = *(const floatx2*)(kn + key * 64 + 32 + pr * 2);
            #pragma unroll
            for (int i = 0; i < 4; ++i) vr[i] = vn[(grp * 4 + i) * 64 + dv];
            kp = pid[pidk + (kc + 1) * 32 + key];
        }

        // fragments (shared across row-tiles)
        half8 kf00 = *(const half8*)&lk[cur][l15 * 64 + ksw0];
        half8 kf01 = *(const half8*)&lk[cur][l15 * 64 + ksw1];
        half8 kf10 = *(const half8*)&lk[cur][(16 + l15) * 64 + ksw0];
        half8 kf11 = *(const half8*)&lk[cur][(16 + l15) * 64 + ksw1];
        half8 vf[4];
        #pragma unroll
        for (int vt = 0; vt < 4; ++vt)
            vf[vt] = *(const half8*)&lvt[cur][(vt * 16 + l15) * 32 + vsw];

        __builtin_amdgcn_s_setprio(1);
        #pragma unroll
        for (int rt = 0; rt < 2; ++rt) {
            // swapped operands: lane holds S^T[key=quad*4+r][q=l15] (s0: keys 0-15, s1: 16-31)
            floatx4 s0 = {0.f,0.f,0.f,0.f}, s1 = {0.f,0.f,0.f,0.f};
            s0 = MFMA_F16(kf00, qf[rt][0], s0, 0, 0, 0);
            s0 = MFMA_F16(kf01, qf[rt][1], s0, 0, 0, 0);
            s1 = MFMA_F16(kf10, qf[rt][0], s1, 0, 0, 0);
            s1 = MFMA_F16(kf11, qf[rt][1], s1, 0, 0, 0);

            // split-K A-operand layout: elements 0-3 -> k=quad*4+i, 4-7 -> k=16+quad*4+i.
            // That is exactly this lane's own s0/s1 -> no cross-lane movement.
            union { unsigned u[4]; half8 h; } pfu;
            pfu.u[0] = pack_f16(__builtin_exp2f(s0[0]), __builtin_exp2f(s0[1]));
            pfu.u[1] = pack_f16(__builtin_exp2f(s0[2]), __builtin_exp2f(s0[3]));
            pfu.u[2] = pack_f16(__builtin_exp2f(s1[0]), __builtin_exp2f(s1[1]));
            pfu.u[3] = pack_f16(__builtin_exp2f(s1[2]), __builtin_exp2f(s1[3]));
            half8 pf = pfu.h;

            ol[rt] = MFMA_F16(pf, onesf, ol[rt], 0, 0, 0);
            #pragma unroll
            for (int vt = 0; vt < 4; ++vt)
                o[rt][vt] = MFMA_F16(pf, vf[vt], o[rt][vt], 0, 0, 0);
        }
        __builtin_amdgcn_s_setprio(0);
    }

    // ---------- epilogue ----------
    #pragma unroll
    for (int rt = 0; rt < 2; ++rt) {
        #pragma unroll
        for (int r = 0; r < 4; ++r) {
            int rowl = wv * 32 + rt * 16 + quad * 4 + r;   // 0..255
            int j = half_ * 256 + rowl;                    // row within window
            float w;
            if (n == 0 || n == 15)  w = 1.0f;
            else if (j < 64)        w = (float)j * (1.0f / 63.0f);
            else if (j >= 448)      w = (float)(511 - j) * (1.0f / 63.0f);
            else                    w = 1.0f;
            float f = (w / (w + 1e-8f)) / ol[rt][r];
            #pragma unroll
            for (int vt = 0; vt < 4; ++vt)
                Ob[rowl * 64 + vt * 16 + l15] = o[rt][vt][r] * f;
        }
    }
}

extern "C" void kernel_launch(void* const* d_in, const int* in_sizes, int n_in,
                              void* d_out, int out_size, void* d_ws, size_t ws_size,
                              hipStream_t stream) {
    const float* q   = (const float*)d_in[0];
    const float* k   = (const float*)d_in[1];
    const float* v   = (const float*)d_in[2];
    const int*   pid = (const int*)d_in[3];
    float* out = (float*)d_out;
    (void)in_sizes; (void)n_in; (void)out_size; (void)d_ws; (void)ws_size;
    swa6<<<dim3(1024), dim3(512), 0, stream>>>(q, k, v, pid, out);
}